// Round 14
// baseline (127.739 us; speedup 1.0000x reference)
//
#include <hip/hip_runtime.h>
#include <hip/hip_bf16.h>
#include <type_traits>

typedef __hip_bfloat16 bf16;
typedef __attribute__((ext_vector_type(4))) float f32x4;
typedef __attribute__((ext_vector_type(8))) short s16x8;

#define DEVINL __device__ __forceinline__

DEVINL s16x8 load16B(const void* p) {
  s16x8 v;
  __builtin_memcpy(&v, __builtin_assume_aligned(p, 16), 16);
  return v;
}
DEVINL void store16B(void* p, s16x8 v) {
  __builtin_memcpy(__builtin_assume_aligned(p, 16), &v, 16);
}
// load 8 consecutive f32, downcast to 8 bf16 packed in s16x8
DEVINL s16x8 cvt8(const float* p) {
  f32x4 a, b;
  __builtin_memcpy(&a, __builtin_assume_aligned(p, 16), 16);
  __builtin_memcpy(&b, __builtin_assume_aligned(p + 4, 16), 16);
  union { s16x8 v; bf16 h[8]; } u;
#pragma unroll
  for (int i = 0; i < 4; i++) {
    u.h[i] = __float2bfloat16(a[i]);
    u.h[4 + i] = __float2bfloat16(b[i]);
  }
  return u.v;
}
// async global->LDS 16B (m97 pattern): LDS dest = wave-uniform base + lane*16
DEVINL void gload_lds16(const bf16* g, bf16* l) {
  __builtin_amdgcn_global_load_lds(
      (__attribute__((address_space(1))) void*)(void*)const_cast<bf16*>(g),
      (__attribute__((address_space(3))) void*)l, 16, 0, 0);
}

static constexpr int SEQ = 2048;   // L
// DX = 1024, H = 16, Dh = 64, B = 2 hard-coded below.
// Q pre-scale: (1/sqrt(DX)) * log2(e)  -> softmax computed in exp2 domain
#define QSCALE 0.04508422002778011f

// ------ weight transpose + downcast: dst[n*1024+k] = bf16(src[k*1024+n]) ---
__global__ __launch_bounds__(256) void k_transpose(
    const float* __restrict__ Wq, const float* __restrict__ Wk,
    const float* __restrict__ Wv, const float* __restrict__ Wo,
    bf16* __restrict__ dst) {
  __shared__ float t[64][65];
  const float* src = blockIdx.z == 0 ? Wq : blockIdx.z == 1 ? Wk
                   : blockIdx.z == 2 ? Wv : Wo;
  bf16* out = dst + (size_t)blockIdx.z * 1024 * 1024;
  const int r0 = blockIdx.y * 64, c0 = blockIdx.x * 64;
#pragma unroll
  for (int i = 0; i < 16; i++) {
    int e = i * 256 + threadIdx.x;
    int r = e >> 6, c = e & 63;
    t[r][c] = src[(size_t)(r0 + r) * 1024 + c0 + c];
  }
  __syncthreads();
#pragma unroll
  for (int i = 0; i < 16; i++) {
    int e = i * 256 + threadIdx.x;
    int r = e >> 6, c = e & 63;
    out[(size_t)(c0 + r) * 1024 + r0 + c] = __float2bfloat16(t[c][r]);
  }
}

// ---- f32 -> bf16 for all three activations in one launch (z selects) ------
__global__ __launch_bounds__(256) void k_cvt3(
    const float* __restrict__ q, const float* __restrict__ k,
    const float* __restrict__ v, bf16* __restrict__ dstbase) {
  const float* src = blockIdx.z == 0 ? q : blockIdx.z == 1 ? k : v;
  bf16* dst = dstbase + (size_t)blockIdx.z * 4194304;
  size_t i = ((size_t)blockIdx.x * 256 + threadIdx.x) * 8;
  store16B(dst + i, cvt8(src + i));
}

// -------- shared GEMM core (R10 structure: single buffer, 2 barriers) ------
// WT bf16 [n][k] staged via global_load_lds; X either bf16 (gload_lds) or
// f32 (reg-stage + cvt + ds_write fallback path).
// mode 0: dst bf16 per-head token-major [bh][l][64], scaled (Q)  / K
// mode 1: dst bf16 per-head d-major     [bh][64][l]  (V^T)
// mode 2: dst f32 natural               [m][1024]    (final out)
template <typename XT>
DEVINL void gemm_core(const XT* __restrict__ X, const bf16* __restrict__ WT,
                      const float* __restrict__ bias, void* __restrict__ dstv,
                      const int mode, const float scale, const int m0,
                      const int n0) {
  __shared__ alignas(16) bf16 As[128 * 32];
  __shared__ alignas(16) bf16 Bs[128 * 32];
  const int tid = threadIdx.x;
  const int w = tid >> 6, lane = tid & 63, lg = lane >> 4, li = lane & 15;
  const int wm = w >> 1, wn = w & 1;

  f32x4 acc[4][4] = {};

  for (int kt = 0; kt < 32; ++kt) {
    const int k0 = kt * 32;
#pragma unroll
    for (int j = 0; j < 2; j++) {
      const int cb = (j * 4 + w) * 64;       // wave-uniform chunk base
      const int c = cb + lane;               // 16B chunk: row=c>>2, k=(c&3)*8
      const int r = c >> 2, kk = (c & 3) * 8;
      gload_lds16(WT + (size_t)(n0 + r) * 1024 + k0 + kk, Bs + cb * 8);
      if constexpr (std::is_same_v<XT, bf16>)
        gload_lds16(X + (size_t)(m0 + r) * 1024 + k0 + kk, As + cb * 8);
    }
    if constexpr (std::is_same_v<XT, float>) {  // fused cvt staging for A
#pragma unroll
      for (int j = 0; j < 2; j++) {
        const int c = j * 256 + tid;
        const int r = c >> 2, kk = (c & 3) * 8;
        s16x8 a = cvt8(X + (size_t)(m0 + r) * 1024 + k0 + kk);
        store16B((char*)As + c * 16, a);
      }
    }
    __syncthreads();   // drains vmcnt+lgkmcnt before s_barrier (m97)
    s16x8 af[4], bfv[4];
#pragma unroll
    for (int i = 0; i < 4; i++)
      af[i] = load16B((char*)As + (wm * 64 + i * 16 + li) * 64 + lg * 16);
#pragma unroll
    for (int j = 0; j < 4; j++)
      bfv[j] = load16B((char*)Bs + (wn * 64 + j * 16 + li) * 64 + lg * 16);
#pragma unroll
    for (int i = 0; i < 4; i++)
#pragma unroll
      for (int j = 0; j < 4; j++)
        acc[i][j] = __builtin_amdgcn_mfma_f32_16x16x32_bf16(af[i], bfv[j],
                                                            acc[i][j], 0, 0, 0);
    __syncthreads();   // all waves done reading before next overwrite
  }

  // C/D layout: lane reg r -> row (lane>>4)*4+r, col lane&15 (m89/m91)
#pragma unroll
  for (int j = 0; j < 4; j++) {
    const int n = n0 + wn * 64 + j * 16 + li;
    const float bv = bias[n];
#pragma unroll
    for (int i = 0; i < 4; i++) {
      const int mrow = m0 + wm * 64 + i * 16 + lg * 4;
      f32x4 a = acc[i][j];
      if (mode == 2) {
        float* dst = (float*)dstv;
#pragma unroll
        for (int r = 0; r < 4; r++)
          dst[(size_t)(mrow + r) * 1024 + n] = a[r] + bv;
      } else if (mode == 0) {
        bf16* dst = (bf16*)dstv;
#pragma unroll
        for (int r = 0; r < 4; r++) {
          int m = mrow + r;   // b=m>>11, l=m&2047, h=n>>6, d=n&63
          size_t idx =
              ((size_t)((m >> 11) * 16 + (n >> 6)) * SEQ + (m & 2047)) * 64 +
              (n & 63);
          dst[idx] = __float2bfloat16((a[r] + bv) * scale);
        }
      } else {  // mode 1: V^T, 4 consecutive tokens same d -> one 8B store
        bf16* dst = (bf16*)dstv;
        size_t base =
            ((size_t)((mrow >> 11) * 16 + (n >> 6)) * 64 + (n & 63)) * SEQ +
            (mrow & 2047);
        bf16 tmp[4];
#pragma unroll
        for (int r = 0; r < 4; r++) tmp[r] = __float2bfloat16(a[r] + bv);
        __builtin_memcpy(__builtin_assume_aligned(dst + base, 8), tmp, 8);
      }
    }
  }
}

// QKV projections, bf16 inputs (pre-converted), all-gload_lds staging.
// grid (x = m-block 32, y = n-block 8, z = 3): id%8 = mx%8 -> co-XCD n-blocks.
__global__ __launch_bounds__(256) void k_gemm_qkv_bf16(
    const bf16* __restrict__ xbase, const bf16* __restrict__ WTbase,
    const float* __restrict__ qb, const float* __restrict__ kb,
    const float* __restrict__ vb, bf16* __restrict__ qo,
    bf16* __restrict__ ko, bf16* __restrict__ vto) {
  const int z = blockIdx.z;
  const bf16* X = xbase + (size_t)z * 4194304;
  const bf16* WT = WTbase + (size_t)z * 1048576;
  const float* bias = z == 0 ? qb : z == 1 ? kb : vb;
  void* dst = z == 0 ? (void*)qo : z == 1 ? (void*)ko : (void*)vto;
  gemm_core<bf16>(X, WT, bias, dst, z == 2 ? 1 : 0, z == 0 ? QSCALE : 1.0f,
                  blockIdx.x * 128, blockIdx.y * 128);
}

// fallback: f32 inputs with fused cvt staging (R10 behavior)
__global__ __launch_bounds__(256) void k_gemm_qkv_f32(
    const float* __restrict__ qx, const float* __restrict__ kx,
    const float* __restrict__ vx, const bf16* __restrict__ WTbase,
    const float* __restrict__ qb, const float* __restrict__ kb,
    const float* __restrict__ vb, bf16* __restrict__ qo,
    bf16* __restrict__ ko, bf16* __restrict__ vto) {
  const int z = blockIdx.z;
  const float* X = z == 0 ? qx : z == 1 ? kx : vx;
  const bf16* WT = WTbase + (size_t)z * 1048576;
  const float* bias = z == 0 ? qb : z == 1 ? kb : vb;
  void* dst = z == 0 ? (void*)qo : z == 1 ? (void*)ko : (void*)vto;
  gemm_core<float>(X, WT, bias, dst, z == 2 ? 1 : 0, z == 0 ? QSCALE : 1.0f,
                   blockIdx.x * 128, blockIdx.y * 128);
}

__global__ __launch_bounds__(256) void k_gemm_out(
    const bf16* __restrict__ X, const bf16* __restrict__ WT,
    const float* __restrict__ bias, float* __restrict__ out) {
  gemm_core<bf16>(X, WT, bias, out, 2, 1.0f, blockIdx.x * 128,
                  blockIdx.y * 128);
}

// ------------------------- causal flash attention --------------------------
// grid (x=bh 32, y=qy 32), qblk = 31-qy (heaviest first; id%8=bh%8 co-XCD).
// SWAPPED QK^T: S^T = mfma(K,Q) -> lane (lg,li) holds 16 scores of q-row li.
// Softmax in EXP2 domain (Q pre-scaled by log2e/32): v_exp_f32 is natively
// 2^x -> no per-element pre-multiply. Tree-structured sum (4 partials).
// Defer-max (T13, THR=8 in log2 => growth < 256x): skip O-rescale when
// __all(mr <= m_run + 8). Double-buffered K/V LDS, 1 barrier/iter.
__global__ __launch_bounds__(256) void k_attn(
    const bf16* __restrict__ qb, const bf16* __restrict__ kb,
    const bf16* __restrict__ vtb, bf16* __restrict__ attn) {
  __shared__ alignas(16) bf16 Ks[2][64 * 64];   // [buf][k][d], XOR-swizzled
  __shared__ alignas(16) bf16 Vts[2][64 * 64];  // [buf][d][k], XOR-swizzled
  __shared__ alignas(16) bf16 Ps[4][16 * 72];   // per-wave P [q=li][k], +8 pad
  const int tid = threadIdx.x;
  const int w = tid >> 6, lane = tid & 63, lg = lane >> 4, li = lane & 15;
  const int bh = blockIdx.x;
  const int qblk = 31 - blockIdx.y;             // heaviest first
  const int qrow = qblk * 64 + w * 16;
  const bf16* qh = qb + (size_t)bh * SEQ * 64;
  const bf16* kh = kb + (size_t)bh * SEQ * 64;
  const bf16* vth = vtb + (size_t)bh * 64 * SEQ;

  s16x8 aq[2];  // Q fragments (B-operand now) held in registers all kernel
#pragma unroll
  for (int c = 0; c < 2; c++)
    aq[c] = load16B(qh + (size_t)(qrow + li) * 64 + c * 32 + lg * 8);

  f32x4 o[4] = {};
  float m_run = -1e38f;   // per-lane: stats of q-row (qrow + li), log2 domain
  float l_run = 0.f;

  // staging helpers (register prefetch -> swizzled LDS write)
  const int c0s = tid, c1s = 256 + tid;
  const int by0 = (c0s * 16) ^ (((c0s >> 3) & 7) << 4);
  const int by1 = (c1s * 16) ^ (((c1s >> 3) & 7) << 4);
  const int d0 = c0s >> 3, kk0 = (c0s & 7) * 8;
  const int d1 = c1s >> 3, kk1 = (c1s & 7) * 8;

  s16x8 rk[2], rv[2];
  // prologue: tile 0 -> regs -> buf0; prefetch tile 1 -> regs
  rk[0] = load16B(kh + (size_t)c0s * 8);
  rk[1] = load16B(kh + (size_t)c1s * 8);
  rv[0] = load16B(vth + (size_t)d0 * SEQ + kk0);
  rv[1] = load16B(vth + (size_t)d1 * SEQ + kk1);
  store16B((char*)Ks[0] + by0, rk[0]);
  store16B((char*)Ks[0] + by1, rk[1]);
  store16B((char*)Vts[0] + by0, rv[0]);
  store16B((char*)Vts[0] + by1, rv[1]);
  if (qblk >= 1) {
    rk[0] = load16B(kh + (size_t)64 * 64 + c0s * 8);
    rk[1] = load16B(kh + (size_t)64 * 64 + c1s * 8);
    rv[0] = load16B(vth + (size_t)d0 * SEQ + 64 + kk0);
    rv[1] = load16B(vth + (size_t)d1 * SEQ + 64 + kk1);
  }
  __syncthreads();

  for (int kbk = 0; kbk <= qblk; ++kbk) {
    const int cur = kbk & 1;
    if (kbk < qblk) {                 // write tile kbk+1 to alt buffer
      store16B((char*)Ks[cur ^ 1] + by0, rk[0]);
      store16B((char*)Ks[cur ^ 1] + by1, rk[1]);
      store16B((char*)Vts[cur ^ 1] + by0, rv[0]);
      store16B((char*)Vts[cur ^ 1] + by1, rv[1]);
      if (kbk + 2 <= qblk) {          // issue loads for tile kbk+2
        const int kn = (kbk + 2) * 64;
        rk[0] = load16B(kh + (size_t)kn * 64 + c0s * 8);
        rk[1] = load16B(kh + (size_t)kn * 64 + c1s * 8);
        rv[0] = load16B(vth + (size_t)d0 * SEQ + kn + kk0);
        rv[1] = load16B(vth + (size_t)d1 * SEQ + kn + kk1);
      }
    }

    // S^T = K Q^T : A-frag = K rows, B-frag = Q rows (log2-domain scores)
    // s[t][r] = S[q = qrow+li][k = kbk*64 + t*16 + lg*4 + r]
    f32x4 s[4];
    __builtin_amdgcn_s_setprio(1);
#pragma unroll
    for (int t = 0; t < 4; t++) {
      f32x4 z = {};
#pragma unroll
      for (int c = 0; c < 2; c++) {
        int row = t * 16 + li;
        s16x8 ak = load16B((char*)Ks[cur] +
                           ((row * 128 + c * 64 + lg * 16) ^ ((row & 7) << 4)));
        z = __builtin_amdgcn_mfma_f32_16x16x32_bf16(ak, aq[c], z, 0, 0, 0);
      }
      s[t] = z;
    }
    __builtin_amdgcn_s_setprio(0);

    if (kbk == qblk) {  // diagonal block: per-element causal mask
      const int kb0 = kbk * 64 + lg * 4;
      const int qg = qrow + li;
#pragma unroll
      for (int t = 0; t < 4; t++)
#pragma unroll
        for (int r = 0; r < 4; r++)
          if (kb0 + t * 16 + r > qg) s[t][r] = -1e30f;
    }

    // row max: in-lane tree + xor16/xor32 (owner lanes {li, li+16/32/48})
    f32x4 mm = s[0];
#pragma unroll
    for (int t = 1; t < 4; t++)
#pragma unroll
      for (int r = 0; r < 4; r++) mm[r] = fmaxf(mm[r], s[t][r]);
    float mr = fmaxf(fmaxf(mm[0], mm[1]), fmaxf(mm[2], mm[3]));
    mr = fmaxf(mr, __shfl_xor(mr, 16));
    mr = fmaxf(mr, __shfl_xor(mr, 32));

    // defer-max: if no lane's row-max grew by >8 (log2) keep old max
    const bool grow = !__all(mr <= m_run + 8.0f);
    const float mn = grow ? fmaxf(m_run, mr) : m_run;

    float p[4][4];
    float s0 = 0.f, s1 = 0.f, s2 = 0.f, s3 = 0.f;   // parallel partials
#pragma unroll
    for (int r = 0; r < 4; r++) {
      float p0 = exp2f(s[0][r] - mn), p1 = exp2f(s[1][r] - mn);
      float p2 = exp2f(s[2][r] - mn), p3 = exp2f(s[3][r] - mn);
      p[0][r] = p0; p[1][r] = p1; p[2][r] = p2; p[3][r] = p3;
      s0 += p0; s1 += p1; s2 += p2; s3 += p3;
    }
    float sum = (s0 + s1) + (s2 + s3);
    sum += __shfl_xor(sum, 16);
    sum += __shfl_xor(sum, 32);

    if (grow) {
      const float cr = exp2f(m_run - mn);
      l_run = l_run * cr + sum;
      m_run = mn;
      const int sb = (lane & 48);
      float crr[4];
#pragma unroll
      for (int r = 0; r < 4; r++) crr[r] = __shfl(cr, sb + (sb >> 2) + r);
#pragma unroll
      for (int t = 0; t < 4; t++)
#pragma unroll
        for (int r = 0; r < 4; r++) o[t][r] *= crr[r];
    } else {
      l_run += sum;
    }

    // P -> per-wave LDS in [q=li][k] layout (8B packed stores)
#pragma unroll
    for (int t = 0; t < 4; t++) {
      bf16 tmp[4];
#pragma unroll
      for (int r = 0; r < 4; r++) tmp[r] = __float2bfloat16(p[t][r]);
      __builtin_memcpy(
          __builtin_assume_aligned(&Ps[w][li * 72 + t * 16 + lg * 4], 8), tmp,
          8);
    }

    s16x8 ap[2];
#pragma unroll
    for (int c = 0; c < 2; c++)
      ap[c] = load16B(&Ps[w][li * 72 + c * 32 + lg * 8]);

    // O += P @ V : B-frag from V^T rows (d = t*16+li)
    __builtin_amdgcn_s_setprio(1);
#pragma unroll
    for (int t = 0; t < 4; t++) {
#pragma unroll
      for (int c = 0; c < 2; c++) {
        int row = t * 16 + li;
        s16x8 bv = load16B((char*)Vts[cur] +
                           ((row * 128 + c * 64 + lg * 16) ^ ((row & 7) << 4)));
        o[t] = __builtin_amdgcn_mfma_f32_16x16x32_bf16(ap[c], bv, o[t], 0, 0, 0);
      }
    }
    __builtin_amdgcn_s_setprio(0);
    __syncthreads();
  }

  const int b = bh >> 4, h = bh & 15;
  const float inv = 1.0f / l_run;
  const int sb = (lane & 48);
  float invr[4];
#pragma unroll
  for (int r = 0; r < 4; r++) invr[r] = __shfl(inv, sb + (sb >> 2) + r);
#pragma unroll
  for (int r = 0; r < 4; r++)
#pragma unroll
    for (int t = 0; t < 4; t++) {
      size_t idx = (size_t)(b * SEQ + qrow + lg * 4 + r) * 1024 + h * 64 +
                   t * 16 + li;
      attn[idx] = __float2bfloat16(o[t][r] * invr[r]);
    }
}

extern "C" void kernel_launch(void* const* d_in, const int* in_sizes, int n_in,
                              void* d_out, int out_size, void* d_ws,
                              size_t ws_size, hipStream_t stream) {
  (void)in_sizes; (void)n_in; (void)out_size;
  const float* value = (const float*)d_in[0];
  const float* key   = (const float*)d_in[1];
  const float* query = (const float*)d_in[2];
  // d_in[3] = mask (int32 causal tril) — causality applied analytically
  const float* Wq_w = (const float*)d_in[4];
  const float* Wq_b = (const float*)d_in[5];
  const float* Wk_w = (const float*)d_in[6];
  const float* Wk_b = (const float*)d_in[7];
  const float* Wv_w = (const float*)d_in[8];
  const float* Wv_b = (const float*)d_in[9];
  // d_in[10..11] = Wr (computed-then-deleted in reference) — skipped
  const float* wo_w = (const float*)d_in[12];
  const float* wo_b = (const float*)d_in[13];

  bf16* ws = (bf16*)d_ws;
  const size_t MM = 1048576;
  bf16* WT = ws;                       // 4 transposed bf16 weights

  k_transpose<<<dim3(16, 16, 4), 256, 0, stream>>>(Wq_w, Wk_w, Wv_w, wo_w, WT);

  if (ws_size >= 28ull * MM * 2) {     // 56 MB: pre-converted bf16 X path
    bf16* xbuf = ws + 4 * MM;          // [3][4096][1024] bf16
    bf16* qbuf = ws + 16 * MM;         // [bh][l][64]
    bf16* kbuf = ws + 20 * MM;
    bf16* vtbf = ws + 24 * MM;         // [bh][64][l]
    bf16* abuf = ws + 4 * MM;          // alias xbuf (dead after QKV GEMM)
    k_cvt3<<<dim3(2048, 1, 3), 256, 0, stream>>>(query, key, value, xbuf);
    k_gemm_qkv_bf16<<<dim3(32, 8, 3), 256, 0, stream>>>(
        xbuf, WT, Wq_b, Wk_b, Wv_b, qbuf, kbuf, vtbf);
    k_attn<<<dim3(32, 32), 256, 0, stream>>>(qbuf, kbuf, vtbf, abuf);
    k_gemm_out<<<dim3(32, 8), 256, 0, stream>>>(abuf, WT + 3 * MM, wo_b,
                                                (float*)d_out);
  } else {                             // 40 MB fallback: fused-cvt (R10)
    bf16* qbuf = ws + 4 * MM;
    bf16* kbuf = ws + 8 * MM;
    bf16* vtbf = ws + 12 * MM;
    bf16* abuf = ws + 16 * MM;
    k_gemm_qkv_f32<<<dim3(32, 8, 3), 256, 0, stream>>>(
        query, key, value, WT, Wq_b, Wk_b, Wv_b, qbuf, kbuf, vtbf);
    k_attn<<<dim3(32, 32), 256, 0, stream>>>(qbuf, kbuf, vtbf, abuf);
    k_gemm_out<<<dim3(32, 8), 256, 0, stream>>>(abuf, WT + 3 * MM, wo_b,
                                                (float*)d_out);
  }
}

// Round 15
// 124.107 us; speedup vs baseline: 1.0293x; 1.0293x over previous
//
#include <hip/hip_runtime.h>
#include <hip/hip_bf16.h>
#include <type_traits>

typedef __hip_bfloat16 bf16;
typedef __attribute__((ext_vector_type(4))) float f32x4;
typedef __attribute__((ext_vector_type(8))) short s16x8;

#define DEVINL __device__ __forceinline__

// raw v_exp_f32 (2^x): our args are <= 0, underflow to 0 is exactly what we want
#if defined(__has_builtin) && __has_builtin(__builtin_amdgcn_exp2f)
#define FEXP2(x) __builtin_amdgcn_exp2f(x)
#else
#define FEXP2(x) __exp2f(x)
#endif

DEVINL s16x8 load16B(const void* p) {
  s16x8 v;
  __builtin_memcpy(&v, __builtin_assume_aligned(p, 16), 16);
  return v;
}
DEVINL void store16B(void* p, s16x8 v) {
  __builtin_memcpy(__builtin_assume_aligned(p, 16), &v, 16);
}
// load 8 consecutive f32, downcast to 8 bf16 packed in s16x8
DEVINL s16x8 cvt8(const float* p) {
  f32x4 a, b;
  __builtin_memcpy(&a, __builtin_assume_aligned(p, 16), 16);
  __builtin_memcpy(&b, __builtin_assume_aligned(p + 4, 16), 16);
  union { s16x8 v; bf16 h[8]; } u;
#pragma unroll
  for (int i = 0; i < 4; i++) {
    u.h[i] = __float2bfloat16(a[i]);
    u.h[4 + i] = __float2bfloat16(b[i]);
  }
  return u.v;
}
// async global->LDS 16B (m97 pattern): LDS dest = wave-uniform base + lane*16
DEVINL void gload_lds16(const bf16* g, bf16* l) {
  __builtin_amdgcn_global_load_lds(
      (__attribute__((address_space(1))) void*)(void*)const_cast<bf16*>(g),
      (__attribute__((address_space(3))) void*)l, 16, 0, 0);
}

static constexpr int SEQ = 2048;   // L
// DX = 1024, H = 16, Dh = 64, B = 2 hard-coded below.
// Q pre-scale: (1/sqrt(DX)) * log2(e)  -> softmax computed in exp2 domain
#define QSCALE 0.04508422002778011f

// ------ weight transpose + downcast: dst[n*1024+k] = bf16(src[k*1024+n]) ---
__global__ __launch_bounds__(256) void k_transpose(
    const float* __restrict__ Wq, const float* __restrict__ Wk,
    const float* __restrict__ Wv, const float* __restrict__ Wo,
    bf16* __restrict__ dst) {
  __shared__ float t[64][65];
  const float* src = blockIdx.z == 0 ? Wq : blockIdx.z == 1 ? Wk
                   : blockIdx.z == 2 ? Wv : Wo;
  bf16* out = dst + (size_t)blockIdx.z * 1024 * 1024;
  const int r0 = blockIdx.y * 64, c0 = blockIdx.x * 64;
#pragma unroll
  for (int i = 0; i < 16; i++) {
    int e = i * 256 + threadIdx.x;
    int r = e >> 6, c = e & 63;
    t[r][c] = src[(size_t)(r0 + r) * 1024 + c0 + c];
  }
  __syncthreads();
#pragma unroll
  for (int i = 0; i < 16; i++) {
    int e = i * 256 + threadIdx.x;
    int r = e >> 6, c = e & 63;
    out[(size_t)(c0 + r) * 1024 + r0 + c] = __float2bfloat16(t[c][r]);
  }
}

// ---- f32 -> bf16 for all three activations in one launch (z selects) ------
__global__ __launch_bounds__(256) void k_cvt3(
    const float* __restrict__ q, const float* __restrict__ k,
    const float* __restrict__ v, bf16* __restrict__ dstbase) {
  const float* src = blockIdx.z == 0 ? q : blockIdx.z == 1 ? k : v;
  bf16* dst = dstbase + (size_t)blockIdx.z * 4194304;
  size_t i = ((size_t)blockIdx.x * 256 + threadIdx.x) * 8;
  store16B(dst + i, cvt8(src + i));
}

// -------- shared GEMM core (R10 structure: single buffer, 2 barriers) ------
// WT bf16 [n][k] staged via global_load_lds; X either bf16 (gload_lds) or
// f32 (reg-stage + cvt + ds_write fallback path).
// mode 0: dst bf16 per-head token-major [bh][l][64], scaled (Q)  / K
// mode 1: dst bf16 per-head d-major     [bh][64][l]  (V^T)
// mode 2: dst f32 natural               [m][1024]    (final out)
template <typename XT>
DEVINL void gemm_core(const XT* __restrict__ X, const bf16* __restrict__ WT,
                      const float* __restrict__ bias, void* __restrict__ dstv,
                      const int mode, const float scale, const int m0,
                      const int n0) {
  __shared__ alignas(16) bf16 As[128 * 32];
  __shared__ alignas(16) bf16 Bs[128 * 32];
  const int tid = threadIdx.x;
  const int w = tid >> 6, lane = tid & 63, lg = lane >> 4, li = lane & 15;
  const int wm = w >> 1, wn = w & 1;

  f32x4 acc[4][4] = {};

  for (int kt = 0; kt < 32; ++kt) {
    const int k0 = kt * 32;
#pragma unroll
    for (int j = 0; j < 2; j++) {
      const int cb = (j * 4 + w) * 64;       // wave-uniform chunk base
      const int c = cb + lane;               // 16B chunk: row=c>>2, k=(c&3)*8
      const int r = c >> 2, kk = (c & 3) * 8;
      gload_lds16(WT + (size_t)(n0 + r) * 1024 + k0 + kk, Bs + cb * 8);
      if constexpr (std::is_same_v<XT, bf16>)
        gload_lds16(X + (size_t)(m0 + r) * 1024 + k0 + kk, As + cb * 8);
    }
    if constexpr (std::is_same_v<XT, float>) {  // fused cvt staging for A
#pragma unroll
      for (int j = 0; j < 2; j++) {
        const int c = j * 256 + tid;
        const int r = c >> 2, kk = (c & 3) * 8;
        s16x8 a = cvt8(X + (size_t)(m0 + r) * 1024 + k0 + kk);
        store16B((char*)As + c * 16, a);
      }
    }
    __syncthreads();   // drains vmcnt+lgkmcnt before s_barrier (m97)
    s16x8 af[4], bfv[4];
#pragma unroll
    for (int i = 0; i < 4; i++)
      af[i] = load16B((char*)As + (wm * 64 + i * 16 + li) * 64 + lg * 16);
#pragma unroll
    for (int j = 0; j < 4; j++)
      bfv[j] = load16B((char*)Bs + (wn * 64 + j * 16 + li) * 64 + lg * 16);
#pragma unroll
    for (int i = 0; i < 4; i++)
#pragma unroll
      for (int j = 0; j < 4; j++)
        acc[i][j] = __builtin_amdgcn_mfma_f32_16x16x32_bf16(af[i], bfv[j],
                                                            acc[i][j], 0, 0, 0);
    __syncthreads();   // all waves done reading before next overwrite
  }

  // C/D layout: lane reg r -> row (lane>>4)*4+r, col lane&15 (m89/m91)
#pragma unroll
  for (int j = 0; j < 4; j++) {
    const int n = n0 + wn * 64 + j * 16 + li;
    const float bv = bias[n];
#pragma unroll
    for (int i = 0; i < 4; i++) {
      const int mrow = m0 + wm * 64 + i * 16 + lg * 4;
      f32x4 a = acc[i][j];
      if (mode == 2) {
        float* dst = (float*)dstv;
#pragma unroll
        for (int r = 0; r < 4; r++)
          dst[(size_t)(mrow + r) * 1024 + n] = a[r] + bv;
      } else if (mode == 0) {
        bf16* dst = (bf16*)dstv;
#pragma unroll
        for (int r = 0; r < 4; r++) {
          int m = mrow + r;   // b=m>>11, l=m&2047, h=n>>6, d=n&63
          size_t idx =
              ((size_t)((m >> 11) * 16 + (n >> 6)) * SEQ + (m & 2047)) * 64 +
              (n & 63);
          dst[idx] = __float2bfloat16((a[r] + bv) * scale);
        }
      } else {  // mode 1: V^T, 4 consecutive tokens same d -> one 8B store
        bf16* dst = (bf16*)dstv;
        size_t base =
            ((size_t)((mrow >> 11) * 16 + (n >> 6)) * 64 + (n & 63)) * SEQ +
            (mrow & 2047);
        bf16 tmp[4];
#pragma unroll
        for (int r = 0; r < 4; r++) tmp[r] = __float2bfloat16(a[r] + bv);
        __builtin_memcpy(__builtin_assume_aligned(dst + base, 8), tmp, 8);
      }
    }
  }
}

// QKV projections, bf16 inputs (pre-converted), all-gload_lds staging.
// grid (x = m-block 32, y = n-block 8, z = 3): id%8 = mx%8 -> co-XCD n-blocks.
__global__ __launch_bounds__(256) void k_gemm_qkv_bf16(
    const bf16* __restrict__ xbase, const bf16* __restrict__ WTbase,
    const float* __restrict__ qb, const float* __restrict__ kb,
    const float* __restrict__ vb, bf16* __restrict__ qo,
    bf16* __restrict__ ko, bf16* __restrict__ vto) {
  const int z = blockIdx.z;
  const bf16* X = xbase + (size_t)z * 4194304;
  const bf16* WT = WTbase + (size_t)z * 1048576;
  const float* bias = z == 0 ? qb : z == 1 ? kb : vb;
  void* dst = z == 0 ? (void*)qo : z == 1 ? (void*)ko : (void*)vto;
  gemm_core<bf16>(X, WT, bias, dst, z == 2 ? 1 : 0, z == 0 ? QSCALE : 1.0f,
                  blockIdx.x * 128, blockIdx.y * 128);
}

// fallback: f32 inputs with fused cvt staging (R10 behavior)
__global__ __launch_bounds__(256) void k_gemm_qkv_f32(
    const float* __restrict__ qx, const float* __restrict__ kx,
    const float* __restrict__ vx, const bf16* __restrict__ WTbase,
    const float* __restrict__ qb, const float* __restrict__ kb,
    const float* __restrict__ vb, bf16* __restrict__ qo,
    bf16* __restrict__ ko, bf16* __restrict__ vto) {
  const int z = blockIdx.z;
  const float* X = z == 0 ? qx : z == 1 ? kx : vx;
  const bf16* WT = WTbase + (size_t)z * 1048576;
  const float* bias = z == 0 ? qb : z == 1 ? kb : vb;
  void* dst = z == 0 ? (void*)qo : z == 1 ? (void*)ko : (void*)vto;
  gemm_core<float>(X, WT, bias, dst, z == 2 ? 1 : 0, z == 0 ? QSCALE : 1.0f,
                   blockIdx.x * 128, blockIdx.y * 128);
}

__global__ __launch_bounds__(256) void k_gemm_out(
    const bf16* __restrict__ X, const bf16* __restrict__ WT,
    const float* __restrict__ bias, float* __restrict__ out) {
  gemm_core<bf16>(X, WT, bias, out, 2, 1.0f, blockIdx.x * 128,
                  blockIdx.y * 128);
}

// ------------------------- causal flash attention --------------------------
// grid (x=bh 32, y=qy 32), qblk = 31-qy (heaviest first; id%8=bh%8 co-XCD).
// SWAPPED QK^T: S^T = mfma(K,Q) -> lane (lg,li) holds 16 scores of q-row li.
// Softmax in EXP2 domain (Q pre-scaled by log2e/32) with RAW v_exp_f32 via
// __builtin_amdgcn_exp2f (R14's exp2f libcall was the regression).
// Tree sum (4 partials) + defer-max (skip O-rescale when growth < 2^8).
__global__ __launch_bounds__(256) void k_attn(
    const bf16* __restrict__ qb, const bf16* __restrict__ kb,
    const bf16* __restrict__ vtb, bf16* __restrict__ attn) {
  __shared__ alignas(16) bf16 Ks[2][64 * 64];   // [buf][k][d], XOR-swizzled
  __shared__ alignas(16) bf16 Vts[2][64 * 64];  // [buf][d][k], XOR-swizzled
  __shared__ alignas(16) bf16 Ps[4][16 * 72];   // per-wave P [q=li][k], +8 pad
  const int tid = threadIdx.x;
  const int w = tid >> 6, lane = tid & 63, lg = lane >> 4, li = lane & 15;
  const int bh = blockIdx.x;
  const int qblk = 31 - blockIdx.y;             // heaviest first
  const int qrow = qblk * 64 + w * 16;
  const bf16* qh = qb + (size_t)bh * SEQ * 64;
  const bf16* kh = kb + (size_t)bh * SEQ * 64;
  const bf16* vth = vtb + (size_t)bh * 64 * SEQ;

  s16x8 aq[2];  // Q fragments (B-operand now) held in registers all kernel
#pragma unroll
  for (int c = 0; c < 2; c++)
    aq[c] = load16B(qh + (size_t)(qrow + li) * 64 + c * 32 + lg * 8);

  f32x4 o[4] = {};
  float m_run = -1e38f;   // per-lane: stats of q-row (qrow + li), log2 domain
  float l_run = 0.f;

  // staging helpers (register prefetch -> swizzled LDS write)
  const int c0s = tid, c1s = 256 + tid;
  const int by0 = (c0s * 16) ^ (((c0s >> 3) & 7) << 4);
  const int by1 = (c1s * 16) ^ (((c1s >> 3) & 7) << 4);
  const int d0 = c0s >> 3, kk0 = (c0s & 7) * 8;
  const int d1 = c1s >> 3, kk1 = (c1s & 7) * 8;

  s16x8 rk[2], rv[2];
  // prologue: tile 0 -> regs -> buf0; prefetch tile 1 -> regs
  rk[0] = load16B(kh + (size_t)c0s * 8);
  rk[1] = load16B(kh + (size_t)c1s * 8);
  rv[0] = load16B(vth + (size_t)d0 * SEQ + kk0);
  rv[1] = load16B(vth + (size_t)d1 * SEQ + kk1);
  store16B((char*)Ks[0] + by0, rk[0]);
  store16B((char*)Ks[0] + by1, rk[1]);
  store16B((char*)Vts[0] + by0, rv[0]);
  store16B((char*)Vts[0] + by1, rv[1]);
  if (qblk >= 1) {
    rk[0] = load16B(kh + (size_t)64 * 64 + c0s * 8);
    rk[1] = load16B(kh + (size_t)64 * 64 + c1s * 8);
    rv[0] = load16B(vth + (size_t)d0 * SEQ + 64 + kk0);
    rv[1] = load16B(vth + (size_t)d1 * SEQ + 64 + kk1);
  }
  __syncthreads();

  for (int kbk = 0; kbk <= qblk; ++kbk) {
    const int cur = kbk & 1;
    if (kbk < qblk) {                 // write tile kbk+1 to alt buffer
      store16B((char*)Ks[cur ^ 1] + by0, rk[0]);
      store16B((char*)Ks[cur ^ 1] + by1, rk[1]);
      store16B((char*)Vts[cur ^ 1] + by0, rv[0]);
      store16B((char*)Vts[cur ^ 1] + by1, rv[1]);
      if (kbk + 2 <= qblk) {          // issue loads for tile kbk+2
        const int kn = (kbk + 2) * 64;
        rk[0] = load16B(kh + (size_t)kn * 64 + c0s * 8);
        rk[1] = load16B(kh + (size_t)kn * 64 + c1s * 8);
        rv[0] = load16B(vth + (size_t)d0 * SEQ + kn + kk0);
        rv[1] = load16B(vth + (size_t)d1 * SEQ + kn + kk1);
      }
    }

    // S^T = K Q^T : A-frag = K rows, B-frag = Q rows (log2-domain scores)
    // s[t][r] = S[q = qrow+li][k = kbk*64 + t*16 + lg*4 + r]
    f32x4 s[4];
    __builtin_amdgcn_s_setprio(1);
#pragma unroll
    for (int t = 0; t < 4; t++) {
      f32x4 z = {};
#pragma unroll
      for (int c = 0; c < 2; c++) {
        int row = t * 16 + li;
        s16x8 ak = load16B((char*)Ks[cur] +
                           ((row * 128 + c * 64 + lg * 16) ^ ((row & 7) << 4)));
        z = __builtin_amdgcn_mfma_f32_16x16x32_bf16(ak, aq[c], z, 0, 0, 0);
      }
      s[t] = z;
    }
    __builtin_amdgcn_s_setprio(0);

    if (kbk == qblk) {  // diagonal block: per-element causal mask
      const int kb0 = kbk * 64 + lg * 4;
      const int qg = qrow + li;
#pragma unroll
      for (int t = 0; t < 4; t++)
#pragma unroll
        for (int r = 0; r < 4; r++)
          if (kb0 + t * 16 + r > qg) s[t][r] = -1e30f;
    }

    // row max: in-lane tree + xor16/xor32 (owner lanes {li, li+16/32/48})
    f32x4 mm = s[0];
#pragma unroll
    for (int t = 1; t < 4; t++)
#pragma unroll
      for (int r = 0; r < 4; r++) mm[r] = fmaxf(mm[r], s[t][r]);
    float mr = fmaxf(fmaxf(mm[0], mm[1]), fmaxf(mm[2], mm[3]));
    mr = fmaxf(mr, __shfl_xor(mr, 16));
    mr = fmaxf(mr, __shfl_xor(mr, 32));

    // defer-max: if no lane's row-max grew by >8 (log2) keep old max
    const bool grow = !__all(mr <= m_run + 8.0f);
    const float mn = grow ? fmaxf(m_run, mr) : m_run;

    float p[4][4];
    float s0 = 0.f, s1 = 0.f, s2 = 0.f, s3 = 0.f;   // parallel partials
#pragma unroll
    for (int r = 0; r < 4; r++) {
      float p0 = FEXP2(s[0][r] - mn), p1 = FEXP2(s[1][r] - mn);
      float p2 = FEXP2(s[2][r] - mn), p3 = FEXP2(s[3][r] - mn);
      p[0][r] = p0; p[1][r] = p1; p[2][r] = p2; p[3][r] = p3;
      s0 += p0; s1 += p1; s2 += p2; s3 += p3;
    }
    float sum = (s0 + s1) + (s2 + s3);
    sum += __shfl_xor(sum, 16);
    sum += __shfl_xor(sum, 32);

    if (grow) {
      const float cr = FEXP2(m_run - mn);
      l_run = l_run * cr + sum;
      m_run = mn;
      const int sb = (lane & 48);
      float crr[4];
#pragma unroll
      for (int r = 0; r < 4; r++) crr[r] = __shfl(cr, sb + (sb >> 2) + r);
#pragma unroll
      for (int t = 0; t < 4; t++)
#pragma unroll
        for (int r = 0; r < 4; r++) o[t][r] *= crr[r];
    } else {
      l_run += sum;
    }

    // P -> per-wave LDS in [q=li][k] layout (8B packed stores)
#pragma unroll
    for (int t = 0; t < 4; t++) {
      bf16 tmp[4];
#pragma unroll
      for (int r = 0; r < 4; r++) tmp[r] = __float2bfloat16(p[t][r]);
      __builtin_memcpy(
          __builtin_assume_aligned(&Ps[w][li * 72 + t * 16 + lg * 4], 8), tmp,
          8);
    }

    s16x8 ap[2];
#pragma unroll
    for (int c = 0; c < 2; c++)
      ap[c] = load16B(&Ps[w][li * 72 + c * 32 + lg * 8]);

    // O += P @ V : B-frag from V^T rows (d = t*16+li)
    __builtin_amdgcn_s_setprio(1);
#pragma unroll
    for (int t = 0; t < 4; t++) {
#pragma unroll
      for (int c = 0; c < 2; c++) {
        int row = t * 16 + li;
        s16x8 bv = load16B((char*)Vts[cur] +
                           ((row * 128 + c * 64 + lg * 16) ^ ((row & 7) << 4)));
        o[t] = __builtin_amdgcn_mfma_f32_16x16x32_bf16(ap[c], bv, o[t], 0, 0, 0);
      }
    }
    __builtin_amdgcn_s_setprio(0);
    __syncthreads();
  }

  const int b = bh >> 4, h = bh & 15;
  const float inv = 1.0f / l_run;
  const int sb = (lane & 48);
  float invr[4];
#pragma unroll
  for (int r = 0; r < 4; r++) invr[r] = __shfl(inv, sb + (sb >> 2) + r);
#pragma unroll
  for (int r = 0; r < 4; r++)
#pragma unroll
    for (int t = 0; t < 4; t++) {
      size_t idx = (size_t)(b * SEQ + qrow + lg * 4 + r) * 1024 + h * 64 +
                   t * 16 + li;
      attn[idx] = __float2bfloat16(o[t][r] * invr[r]);
    }
}

extern "C" void kernel_launch(void* const* d_in, const int* in_sizes, int n_in,
                              void* d_out, int out_size, void* d_ws,
                              size_t ws_size, hipStream_t stream) {
  (void)in_sizes; (void)n_in; (void)out_size;
  const float* value = (const float*)d_in[0];
  const float* key   = (const float*)d_in[1];
  const float* query = (const float*)d_in[2];
  // d_in[3] = mask (int32 causal tril) — causality applied analytically
  const float* Wq_w = (const float*)d_in[4];
  const float* Wq_b = (const float*)d_in[5];
  const float* Wk_w = (const float*)d_in[6];
  const float* Wk_b = (const float*)d_in[7];
  const float* Wv_w = (const float*)d_in[8];
  const float* Wv_b = (const float*)d_in[9];
  // d_in[10..11] = Wr (computed-then-deleted in reference) — skipped
  const float* wo_w = (const float*)d_in[12];
  const float* wo_b = (const float*)d_in[13];

  bf16* ws = (bf16*)d_ws;
  const size_t MM = 1048576;
  bf16* WT = ws;                       // 4 transposed bf16 weights

  k_transpose<<<dim3(16, 16, 4), 256, 0, stream>>>(Wq_w, Wk_w, Wv_w, wo_w, WT);

  if (ws_size >= 28ull * MM * 2) {     // 56 MB: pre-converted bf16 X path
    bf16* xbuf = ws + 4 * MM;          // [3][4096][1024] bf16
    bf16* qbuf = ws + 16 * MM;         // [bh][l][64]
    bf16* kbuf = ws + 20 * MM;
    bf16* vtbf = ws + 24 * MM;         // [bh][64][l]
    bf16* abuf = ws + 4 * MM;          // alias xbuf (dead after QKV GEMM)
    k_cvt3<<<dim3(2048, 1, 3), 256, 0, stream>>>(query, key, value, xbuf);
    k_gemm_qkv_bf16<<<dim3(32, 8, 3), 256, 0, stream>>>(
        xbuf, WT, Wq_b, Wk_b, Wv_b, qbuf, kbuf, vtbf);
    k_attn<<<dim3(32, 32), 256, 0, stream>>>(qbuf, kbuf, vtbf, abuf);
    k_gemm_out<<<dim3(32, 8), 256, 0, stream>>>(abuf, WT + 3 * MM, wo_b,
                                                (float*)d_out);
  } else {                             // 40 MB fallback: fused-cvt (R10)
    bf16* qbuf = ws + 4 * MM;
    bf16* kbuf = ws + 8 * MM;
    bf16* vtbf = ws + 12 * MM;
    bf16* abuf = ws + 16 * MM;
    k_gemm_qkv_f32<<<dim3(32, 8, 3), 256, 0, stream>>>(
        query, key, value, WT, Wq_b, Wk_b, Wv_b, qbuf, kbuf, vtbf);
    k_attn<<<dim3(32, 32), 256, 0, stream>>>(qbuf, kbuf, vtbf, abuf);
    k_gemm_out<<<dim3(32, 8), 256, 0, stream>>>(abuf, WT + 3 * MM, wo_b,
                                                (float*)d_out);
  }
}